// Round 1
// baseline (179.133 us; speedup 1.0000x reference)
//
#include <hip/hip_runtime.h>

#define IH 512
#define IW 512
#define OH 502
#define OW 502
#define KS 11
#define TILE 32
#define IN_T (TILE + KS - 1)   /* 42 */
#define NCH 48                  /* 16*3 */
#define TPD 16                  /* ceil(502/32) tiles per dim */
#define C1 0.0001f
#define C2 0.0009f

// Gaussian(sigma=1.5, k=11) weights, precomputed in double precision.
__device__ __constant__ float g_w[KS] = {
    0.00102838f, 0.00759876f, 0.03600077f, 0.10936069f, 0.21300554f,
    0.26601173f, 0.21300554f, 0.10936069f, 0.03600077f, 0.00759876f,
    0.00102838f};

__global__ void zero_acc(double* acc) {
    if (threadIdx.x == 0) acc[0] = 0.0;
}

__global__ __launch_bounds__(256) void ssim_main(const float* __restrict__ x,
                                                 const float* __restrict__ y,
                                                 double* __restrict__ acc) {
    __shared__ float xs[IN_T * IN_T];
    __shared__ float ys[IN_T * IN_T];
    __shared__ float v0[TILE * IN_T];
    __shared__ float v1[TILE * IN_T];
    __shared__ float v2[TILE * IN_T];
    __shared__ float v3[TILE * IN_T];
    __shared__ float v4[TILE * IN_T];
    __shared__ float red[4];

    const int bid = blockIdx.x;
    const int ch = bid / (TPD * TPD);
    const int tile = bid % (TPD * TPD);
    const int ti = tile / TPD, tj = tile % TPD;
    const int row0 = ti * TILE, col0 = tj * TILE;
    const float* __restrict__ xc = x + (size_t)ch * IH * IW;
    const float* __restrict__ yc = y + (size_t)ch * IH * IW;
    const int tid = threadIdx.x;

    // ---- stage 1: load 42x42 input tiles (clamped at image edge; clamped
    // region only feeds discarded out-of-range outputs) ----
    for (int idx = tid; idx < IN_T * IN_T; idx += 256) {
        const int r = idx / IN_T, c = idx % IN_T;
        const int gr = min(row0 + r, IH - 1);
        const int gc = min(col0 + c, IW - 1);
        const float xv = xc[gr * IW + gc];
        const float yv = yc[gr * IW + gc];
        xs[idx] = xv;
        ys[idx] = yv;
    }
    __syncthreads();

    // ---- stage 2: vertical blur of 5 quantities (products on the fly) ----
    for (int idx = tid; idx < TILE * IN_T; idx += 256) {
        const int r = idx / IN_T, c = idx % IN_T;
        float s0 = 0.f, s1 = 0.f, s2 = 0.f, s3 = 0.f, s4 = 0.f;
#pragma unroll
        for (int t = 0; t < KS; ++t) {
            const float wt = g_w[t];
            const float xv = xs[(r + t) * IN_T + c];
            const float yv = ys[(r + t) * IN_T + c];
            s0 += wt * xv;
            s1 += wt * yv;
            s2 += wt * xv * xv;
            s3 += wt * yv * yv;
            s4 += wt * xv * yv;
        }
        v0[idx] = s0;
        v1[idx] = s1;
        v2[idx] = s2;
        v3[idx] = s3;
        v4[idx] = s4;
    }
    __syncthreads();

    // ---- stage 3: horizontal blur + ssim + local sum ----
    float lsum = 0.f;
    for (int idx = tid; idx < TILE * TILE; idx += 256) {
        const int r = idx / TILE, c = idx % TILE;
        const int gr = row0 + r, gc = col0 + c;
        if (gr < OH && gc < OW) {
            const int base = r * IN_T + c;
            float m0 = 0.f, m1 = 0.f, m2 = 0.f, m3 = 0.f, m4 = 0.f;
#pragma unroll
            for (int t = 0; t < KS; ++t) {
                const float wt = g_w[t];
                m0 += wt * v0[base + t];
                m1 += wt * v1[base + t];
                m2 += wt * v2[base + t];
                m3 += wt * v3[base + t];
                m4 += wt * v4[base + t];
            }
            const float mux2 = m0 * m0;
            const float muy2 = m1 * m1;
            const float muxy = m0 * m1;
            const float vx = m2 - mux2;
            const float vy = m3 - muy2;
            const float cxy = m4 - muxy;
            const float num = (2.f * muxy + C1) * (2.f * cxy + C2);
            const float den = (mux2 + muy2 + C1) * (vx + vy + C2);
            lsum += num / den;
        }
    }

    // ---- block reduce (4 waves of 64) ----
#pragma unroll
    for (int off = 32; off > 0; off >>= 1) lsum += __shfl_down(lsum, off, 64);
    const int wave = tid >> 6, lane = tid & 63;
    if (lane == 0) red[wave] = lsum;
    __syncthreads();
    if (tid == 0) {
        const float bs = red[0] + red[1] + red[2] + red[3];
        atomicAdd(acc, (double)bs);
    }
}

__global__ void finalize(const double* __restrict__ acc, float* __restrict__ out) {
    if (threadIdx.x == 0) {
        out[0] = (float)(1.0 - acc[0] / 12096192.0);  // 48*502*502
    }
}

extern "C" void kernel_launch(void* const* d_in, const int* in_sizes, int n_in,
                              void* d_out, int out_size, void* d_ws, size_t ws_size,
                              hipStream_t stream) {
    const float* x = (const float*)d_in[0];
    const float* y = (const float*)d_in[1];
    float* out = (float*)d_out;
    double* acc = (double*)d_ws;

    zero_acc<<<1, 64, 0, stream>>>(acc);
    ssim_main<<<NCH * TPD * TPD, 256, 0, stream>>>(x, y, acc);
    finalize<<<1, 64, 0, stream>>>(acc, out);
}